// Round 1
// baseline (2218.086 us; speedup 1.0000x reference)
//
#include <hip/hip_runtime.h>
#include <hip/hip_bf16.h>

#define HH 512
#define FF 128
#define BB 2048
#define TT 96
#define NTOT 2176  // 2048 interleaved gate cols + 128 fc_w.T cols

typedef short short8 __attribute__((ext_vector_type(8)));
typedef float f32x4 __attribute__((ext_vector_type(4)));

__device__ __forceinline__ float sigmoidf_(float x) {
    return 1.f / (1.f + __expf(-x));
}
__device__ __forceinline__ float tanhf_(float x) {
    // stable: e in (0,1], no overflow
    float e = __expf(-2.f * fabsf(x));
    float t = (1.f - e) / (1.f + e);
    return x < 0.f ? -t : t;
}

// Build W_full^T (row-major by n, K=512 contiguous) in bf16, plus biases.
// n layout: n < 2048: s = n>>6 selects j-slice of 16; within 64: [r(16) z(16) i_n(16) h_n(16)]
//   r/z cols:  w_hh[g][k] + sum_f w_ih[g][f]*fc_w[f][k]
//   i_n cols:  sum_f w_ih[1024+j][f]*fc_w[f][k]
//   h_n cols:  w_hh[1024+j][k]
// n >= 2048: f = n-2048: fc_w[f][k]
// W0 (step 0, x=0): same but without the w_ih@fc_w terms. Biases likewise.
__global__ __launch_bounds__(256) void build_weights(
    const float* __restrict__ w_ih, const float* __restrict__ w_hh,
    const float* __restrict__ b_ih, const float* __restrict__ b_hh,
    const float* __restrict__ fc_w, const float* __restrict__ fc_b,
    __hip_bfloat16* __restrict__ Wt, __hip_bfloat16* __restrict__ W0t,
    float* __restrict__ bias, float* __restrict__ bias0)
{
    const int n = blockIdx.x;
    const int tid = threadIdx.x;
    __shared__ float wih_s[FF];
    const bool is_out = (n >= 2048);
    int gate = 3, gidx = 0, f = 0;
    if (is_out) {
        f = n - 2048;
    } else {
        int s = n >> 6, r6 = n & 63;
        gate = r6 >> 4;
        int jj = r6 & 15;
        int j = s * 16 + jj;
        gidx = (gate == 0) ? j : (gate == 1) ? (512 + j) : (1024 + j);
    }
    if (!is_out && gate != 3 && tid < FF) wih_s[tid] = w_ih[gidx * FF + tid];
    __syncthreads();

    for (int k = tid; k < HH; k += 256) {
        float w, w0;
        if (is_out) {
            w = fc_w[f * HH + k];
            w0 = 0.f;
        } else if (gate == 3) {
            w = w_hh[gidx * HH + k];
            w0 = w;
        } else {
            float comb = 0.f;
#pragma unroll 8
            for (int ff2 = 0; ff2 < FF; ++ff2) comb += wih_s[ff2] * fc_w[ff2 * HH + k];
            if (gate == 2) { w = comb; w0 = 0.f; }
            else { float whh = w_hh[gidx * HH + k]; w = whh + comb; w0 = whh; }
        }
        Wt[n * HH + k]  = __float2bfloat16(w);
        W0t[n * HH + k] = __float2bfloat16(w0);
    }
    if (tid == 0) {
        float b, b0;
        if (is_out) { b = fc_b[f]; b0 = 0.f; }
        else {
            float cb = 0.f;
            if (gate != 3)
                for (int ff2 = 0; ff2 < FF; ++ff2) cb += fc_b[ff2] * w_ih[gidx * FF + ff2];
            if (gate <= 1)      { float s2 = b_ih[gidx] + b_hh[gidx]; b = s2 + cb; b0 = s2; }
            else if (gate == 2) { b = b_ih[gidx] + cb; b0 = b_ih[gidx]; }
            else                { b = b_hh[gidx]; b0 = b_hh[gidx]; }
        }
        bias[n] = b; bias0[n] = b0;
    }
}

__global__ __launch_bounds__(256) void init_h(
    const float* __restrict__ hidden, float* __restrict__ hf,
    __hip_bfloat16* __restrict__ hb, int nElem)
{
    int i = blockIdx.x * 256 + threadIdx.x;
    if (i < nElem) {
        float v = hidden[i];
        hf[i] = v;
        hb[i] = __float2bfloat16(v);
    }
}

// One GRU step (fused GEMM + gates + output projection).
// Grid: (colBlocks, 16). Block tile: 128 rows x 64 n-cols, BK=64, 256 threads = 4 waves,
// each wave handles 32 rows x 64 cols = 2x4 MFMA 16x16 tiles.
// cb < 32: gate cols -> compute h_new (block covers j-slice of 16: all 4 gates per lane regs)
// cb >= 32: fc cols  -> write x_t = h_t @ fc_w.T + fc_b to out[:, tt, :]
__global__ __launch_bounds__(256) void gru_step(
    const __hip_bfloat16* __restrict__ Wt, const float* __restrict__ bias,
    const __hip_bfloat16* __restrict__ h_in_b, const float* __restrict__ h_in_f,
    __hip_bfloat16* __restrict__ h_out_b, float* __restrict__ h_out_f,
    float* __restrict__ out, int tt, int col_base)
{
    __shared__ __align__(16) short A_s[128][72]; // h tile, +8 pad breaks bank aliasing
    __shared__ __align__(16) short B_s[64][72];  // W tile (n-major)

    const int tid = threadIdx.x;
    const int lane = tid & 63, w = tid >> 6;
    const int l15 = lane & 15, quad = lane >> 4;
    const int cb = col_base + blockIdx.x;
    const int row_base = blockIdx.y * 128;
    const int n_base = cb * 64;
    const short* hb = (const short*)h_in_b;
    const short* wt = (const short*)Wt;

    f32x4 acc[2][4];
#pragma unroll
    for (int nt = 0; nt < 4; ++nt) {
        float bv = bias[n_base + nt * 16 + l15];
        acc[0][nt] = (f32x4){bv, bv, bv, bv};
        acc[1][nt] = acc[0][nt];
    }

    for (int kt = 0; kt < 8; ++kt) {
        const int k0 = kt * 64;
#pragma unroll
        for (int i = 0; i < 4; ++i) {
            int c = tid + i * 256, row = c >> 3, ch = (c & 7) * 8;
            *(int4*)&A_s[row][ch] = *(const int4*)&hb[(row_base + row) * HH + k0 + ch];
        }
#pragma unroll
        for (int i = 0; i < 2; ++i) {
            int c = tid + i * 256, row = c >> 3, ch = (c & 7) * 8;
            *(int4*)&B_s[row][ch] = *(const int4*)&wt[(n_base + row) * HH + k0 + ch];
        }
        __syncthreads();
#pragma unroll
        for (int ks = 0; ks < 2; ++ks) {
            const int kk = ks * 32 + quad * 8;
            short8 a0 = *(const short8*)&A_s[w * 32 + l15][kk];
            short8 a1 = *(const short8*)&A_s[w * 32 + 16 + l15][kk];
            short8 b0 = *(const short8*)&B_s[l15][kk];
            short8 b1 = *(const short8*)&B_s[16 + l15][kk];
            short8 b2 = *(const short8*)&B_s[32 + l15][kk];
            short8 b3 = *(const short8*)&B_s[48 + l15][kk];
            acc[0][0] = __builtin_amdgcn_mfma_f32_16x16x32_bf16(a0, b0, acc[0][0], 0, 0, 0);
            acc[0][1] = __builtin_amdgcn_mfma_f32_16x16x32_bf16(a0, b1, acc[0][1], 0, 0, 0);
            acc[0][2] = __builtin_amdgcn_mfma_f32_16x16x32_bf16(a0, b2, acc[0][2], 0, 0, 0);
            acc[0][3] = __builtin_amdgcn_mfma_f32_16x16x32_bf16(a0, b3, acc[0][3], 0, 0, 0);
            acc[1][0] = __builtin_amdgcn_mfma_f32_16x16x32_bf16(a1, b0, acc[1][0], 0, 0, 0);
            acc[1][1] = __builtin_amdgcn_mfma_f32_16x16x32_bf16(a1, b1, acc[1][1], 0, 0, 0);
            acc[1][2] = __builtin_amdgcn_mfma_f32_16x16x32_bf16(a1, b2, acc[1][2], 0, 0, 0);
            acc[1][3] = __builtin_amdgcn_mfma_f32_16x16x32_bf16(a1, b3, acc[1][3], 0, 0, 0);
        }
        __syncthreads();
    }

    if (cb < 32) {
        // gate epilogue: nt 0..3 = r, z, i_n, h_n for j = cb*16 + l15
        const int j = cb * 16 + l15;
#pragma unroll
        for (int mt = 0; mt < 2; ++mt) {
#pragma unroll
            for (int rg = 0; rg < 4; ++rg) {
                int brow = row_base + w * 32 + mt * 16 + quad * 4 + rg;
                float r = sigmoidf_(acc[mt][0][rg]);
                float z = sigmoidf_(acc[mt][1][rg]);
                float nv = tanhf_(acc[mt][2][rg] + r * acc[mt][3][rg]);
                float hold = h_in_f[brow * HH + j];
                float hnew = (1.f - z) * nv + z * hold;
                h_out_f[brow * HH + j] = hnew;
                h_out_b[brow * HH + j] = __float2bfloat16(hnew);
            }
        }
    } else {
        const int fb = (cb - 32) * 64;
#pragma unroll
        for (int mt = 0; mt < 2; ++mt)
#pragma unroll
            for (int nt = 0; nt < 4; ++nt)
#pragma unroll
                for (int rg = 0; rg < 4; ++rg) {
                    int brow = row_base + w * 32 + mt * 16 + quad * 4 + rg;
                    out[(brow * TT + tt) * FF + fb + nt * 16 + l15] = acc[mt][nt][rg];
                }
    }
}

extern "C" void kernel_launch(void* const* d_in, const int* in_sizes, int n_in,
                              void* d_out, int out_size, void* d_ws, size_t ws_size,
                              hipStream_t stream) {
    const float* hidden = (const float*)d_in[0];
    const float* w_ih   = (const float*)d_in[1];
    const float* w_hh   = (const float*)d_in[2];
    const float* b_ih   = (const float*)d_in[3];
    const float* b_hh   = (const float*)d_in[4];
    const float* fc_w   = (const float*)d_in[5];
    const float* fc_b   = (const float*)d_in[6];
    float* out = (float*)d_out;

    char* ws = (char*)d_ws;
    size_t off = 0;
    auto alloc = [&](size_t bytes) -> void* {
        void* p = ws + off;
        off += (bytes + 255) & ~(size_t)255;
        return p;
    };
    __hip_bfloat16* Wt  = (__hip_bfloat16*)alloc((size_t)NTOT * HH * 2);
    __hip_bfloat16* W0t = (__hip_bfloat16*)alloc((size_t)NTOT * HH * 2);
    float* bias  = (float*)alloc(NTOT * 4);
    float* bias0 = (float*)alloc(NTOT * 4);
    float* hf0 = (float*)alloc((size_t)BB * HH * 4);
    float* hf1 = (float*)alloc((size_t)BB * HH * 4);
    __hip_bfloat16* hb0 = (__hip_bfloat16*)alloc((size_t)BB * HH * 2);
    __hip_bfloat16* hb1 = (__hip_bfloat16*)alloc((size_t)BB * HH * 2);
    float* hf[2] = {hf0, hf1};
    __hip_bfloat16* hbp[2] = {hb0, hb1};

    build_weights<<<NTOT, 256, 0, stream>>>(w_ih, w_hh, b_ih, b_hh, fc_w, fc_b,
                                            Wt, W0t, bias, bias0);
    init_h<<<(BB * HH + 255) / 256, 256, 0, stream>>>(hidden, hf0, hb0, BB * HH);

    // t = 0: uses W0 (x=0), gate blocks only (no output yet)
    gru_step<<<dim3(32, 16), 256, 0, stream>>>(W0t, bias0, hbp[0], hf[0],
                                               hbp[1], hf[1], out, 0, 0);
    // t = 1..95: full step, also writes x_t -> out[:, 96-t, :]
    for (int t = 1; t <= 95; ++t) {
        gru_step<<<dim3(34, 16), 256, 0, stream>>>(Wt, bias, hbp[t & 1], hf[t & 1],
                                                   hbp[(t + 1) & 1], hf[(t + 1) & 1],
                                                   out, 96 - t, 0);
    }
    // t = 96: output-only blocks (x_96 -> out[:, 0, :])
    gru_step<<<dim3(2, 16), 256, 0, stream>>>(Wt, bias, hbp[0], hf[0],
                                              hbp[1], hf[1], out, 0, 32);
}